// Round 10
// baseline (335.876 us; speedup 1.0000x reference)
//
#include <hip/hip_runtime.h>
#include <hip/hip_bf16.h>

// Problem constants (T=2048, B=32, N=1024, H=8, K=128, K2=16)
#define T_DIM 2048
#define B_DIM 32
#define N_DIM 1024
#define H_DIM 8
#define K_DIM 128
#define Q_DIM 16

typedef __bf16 bf16x8 __attribute__((ext_vector_type(8)));
typedef __bf16 bf16x4 __attribute__((ext_vector_type(4)));
typedef float  f32x4  __attribute__((ext_vector_type(4)));

__device__ inline bf16x8 cvt8(float4 a, float4 b) {
    bf16x8 r;
    r[0] = (__bf16)a.x; r[1] = (__bf16)a.y; r[2] = (__bf16)a.z; r[3] = (__bf16)a.w;
    r[4] = (__bf16)b.x; r[5] = (__bf16)b.y; r[6] = (__bf16)b.z; r[7] = (__bf16)b.w;
    return r;
}

// ---------------------------------------------------------------------------
// K0: f32 -> bf16 convert (only Wmh now, 1M elems).
// ---------------------------------------------------------------------------
__global__ __launch_bounds__(256)
void cvt_f32_bf16(const float* __restrict__ s, __bf16* __restrict__ d)
{
    const long i = ((long)blockIdx.x * 256 + threadIdx.x) * 8;
    float4 a = *(const float4*)(s + i);
    float4 b = *(const float4*)(s + i + 4);
    *(bf16x8*)(d + i) = cvt8(a, b);
}

// ---------------------------------------------------------------------------
// K1: 8-phase 256x256 GEMM with A read DIRECTLY from f32 hyp (fused cvt).
// A path (T14 async-split): at KT i ph1, ds_write A(i+1) (cvt from f32 regs
// loaded at KT i-1 ph1) into slot s^1 [safe: s^1's A last read at KT i-1 ph4,
// lgkm0+barrier before the write], then issue 8x global_load_dwordx4 of
// A(i+2) f32 [4 phases in flight >> HBM latency; compiler auto-waits the
// ds_write dep]. B path unchanged: global_load_lds of B(i+2) at ph3/ph4 into
// slot s. Steady vmcnt(12) at ph4 retires B(i+1): outstanding order =
// [B(i+1) 4][A(i+2) 8][B(i+2) 4]. Tails: KT14 vmcnt(0), KT15 none.
// Operand-swapped MFMA (transposed D), XOR-swizzled LDS, unroll-by-2 (all ds
// offsets 16-bit immediates). Fused time-mean partials in epilogue.
// ---------------------------------------------------------------------------
__global__ __launch_bounds__(512, 1)
void gemm_x_8ph(const float* __restrict__ A, const __bf16* __restrict__ Bw,
                const float* __restrict__ bias, __bf16* __restrict__ X,
                float* __restrict__ mpart)
{
    __shared__ __bf16 ldsA[2][16384];   // [slot][256 rows * 64 k]
    __shared__ __bf16 ldsB[2][16384];
    __bf16* ldsAf = &ldsA[0][0];
    __bf16* ldsBf = &ldsB[0][0];

    const int tid  = threadIdx.x;
    const int lane = tid & 63;
    const int w    = tid >> 6;     // 0..7
    const int wm   = w >> 2;       // 0..1 -> 128 rows
    const int wn   = w & 3;        // 0..3 -> 64 cols

    const int bid  = blockIdx.x;                    // 1024 blocks, %8==0
    const int wgid = (bid & 7) * 128 + (bid >> 3);  // bijective XCD swizzle
    const int bm   = wgid >> 2;                     // 0..255
    const int bn   = wgid & 3;                      // 0..3
    const long row0 = (long)bm * 256;
    const long col0 = (long)bn * 256;

    // staging geometry: thread covers row j*64 + w*8 + (lane>>3), swizzled
    // chunk (lane&7)^(lane>>3) (= c ^ (row&7)); LDS dest = slot + j*4096 +
    // w*512 + lane*8 (linear per wave).
    const int srow = w * 8 + (lane >> 3);
    const int scol = ((lane & 7) ^ (lane >> 3)) * 8;
    const float*  Af = A  + (row0 + srow) * 1024 + scol;   // f32 source
    const __bf16* Bg = Bw + (col0 + srow) * 1024 + scol;
    const int ldst = w * 512;
    __bf16* ldsAw = ldsAf + ldst + (lane & 63) * 8;   // per-lane A write base

    const int fr = lane & 15;
    const int g2 = lane >> 4;    // 0..3: 16B chunk within k-half
    const int x7 = lane & 7;     // read-side XOR key

    // per-thread LDS read bases; reads = base + compile-time immediate.
    const __bf16* aK0 = ldsAf + (wm * 128 + fr) * 64 + ((g2    ) ^ x7) * 8;
    const __bf16* aK1 = ldsAf + (wm * 128 + fr) * 64 + ((4 + g2) ^ x7) * 8;
    const __bf16* bK0 = ldsBf + (wn * 64  + fr) * 64 + ((g2    ) ^ x7) * 8;
    const __bf16* bK1 = ldsBf + (wn * 64  + fr) * 64 + ((4 + g2) ^ x7) * 8;

    f32x4 acc[8][4];
    #pragma unroll
    for (int i = 0; i < 8; ++i)
        #pragma unroll
        for (int j = 0; j < 4; ++j)
            acc[i][j] = f32x4{0.f, 0.f, 0.f, 0.f};

    #define GLDA(SRC_, DST_) __builtin_amdgcn_global_load_lds( \
        (const __attribute__((address_space(1))) void*)(SRC_), \
        (__attribute__((address_space(3))) void*)(DST_), 16, 0, 0)

    // ---- prologue ----
    float4 rA[8];
    // A(KT0) f32 -> regs
    #pragma unroll
    for (int j = 0; j < 4; ++j) {
        rA[2*j]   = *(const float4*)(Af + (long)j * 65536);
        rA[2*j+1] = *(const float4*)(Af + (long)j * 65536 + 4);
    }
    // B(KT0), B(KT1) via gload_lds
    #pragma unroll
    for (int j = 0; j < 2; ++j) GLDA(Bg + (long)j * 65536,               ldsBf + j * 4096 + ldst);
    #pragma unroll
    for (int j = 0; j < 2; ++j) GLDA(Bg + 131072 + (long)j * 65536,      ldsBf + 8192 + j * 4096 + ldst);
    #pragma unroll
    for (int j = 0; j < 2; ++j) GLDA(Bg + 64 + (long)j * 65536,          ldsBf + 16384 + j * 4096 + ldst);
    #pragma unroll
    for (int j = 0; j < 2; ++j) GLDA(Bg + 64 + 131072 + (long)j * 65536, ldsBf + 16384 + 8192 + j * 4096 + ldst);
    // ds_write A(KT0) -> slot0 (compiler auto-waits the rA loads)
    *(bf16x8*)(ldsAw        ) = cvt8(rA[0], rA[1]);
    *(bf16x8*)(ldsAw +  4096) = cvt8(rA[2], rA[3]);
    *(bf16x8*)(ldsAw +  8192) = cvt8(rA[4], rA[5]);
    *(bf16x8*)(ldsAw + 12288) = cvt8(rA[6], rA[7]);
    // A(KT1) f32 -> regs (written at KT0 ph1)
    #pragma unroll
    for (int j = 0; j < 4; ++j) {
        rA[2*j]   = *(const float4*)(Af + 64 + (long)j * 65536);
        rA[2*j+1] = *(const float4*)(Af + 64 + (long)j * 65536 + 4);
    }
    // B(KT0) landed (leaves B(KT1) 4 + A(KT1) 8 in flight)
    asm volatile("s_waitcnt vmcnt(12)" ::: "memory");
    __builtin_amdgcn_sched_barrier(0);
    asm volatile("s_waitcnt lgkmcnt(0)" ::: "memory");   // A writes visible
    __builtin_amdgcn_sched_barrier(0);
    __builtin_amdgcn_s_barrier();

    const float*  AfN = Af + 128;   // A(KT2) f32 source
    const __bf16* BgN = Bg + 128;   // B(KT2) source

    #define MFMA16(AF_, BF_, OFF_)                                             \
        __builtin_amdgcn_s_setprio(1);                                         \
        _Pragma("unroll") for (int mi = 0; mi < 4; ++mi)                       \
            _Pragma("unroll") for (int ni = 0; ni < 4; ++ni)                   \
                acc[mi + (OFF_)][ni] = __builtin_amdgcn_mfma_f32_16x16x32_bf16(\
                    BF_[ni], AF_[mi], acc[mi + (OFF_)][ni], 0, 0, 0);          \
        __builtin_amdgcn_s_setprio(0);

    #define LGKM0()                                                            \
        asm volatile("s_waitcnt lgkmcnt(0)" ::: "memory");                     \
        __builtin_amdgcn_sched_barrier(0);

    // One K-tile = 4 phases. SO_/SN_: this/other slot offset. KO_: 0|64.
    // STGAW_: ds_write A(KT+1) (regs->slot SN). STGAL_: issue A(KT+2) f32
    // loads. STGB_: gload B(KT+2) -> slot SO. VM_: 12 / 0 / -1 at ph4.
    #define KTBODY(SO_, SN_, KO_, STGAW_, STGAL_, STGB_, VM_)                  \
    {                                                                          \
        bf16x8 a0[4], b0[4], a0h[4], b1[4], a1[4], a1h[4];                     \
        /* ph1: read a0,b0; write A(KT+1); issue A(KT+2) loads */              \
        _Pragma("unroll") for (int mi = 0; mi < 4; ++mi)                       \
            a0[mi] = *(const bf16x8*)(aK0 + (SO_) + mi * 1024);                \
        _Pragma("unroll") for (int ni = 0; ni < 4; ++ni)                       \
            b0[ni] = *(const bf16x8*)(bK0 + (SO_) + ni * 1024);                \
        if (STGAW_) {                                                          \
            *(bf16x8*)(ldsAw + (SN_)        ) = cvt8(rA[0], rA[1]);            \
            *(bf16x8*)(ldsAw + (SN_) +  4096) = cvt8(rA[2], rA[3]);            \
            *(bf16x8*)(ldsAw + (SN_) +  8192) = cvt8(rA[4], rA[5]);            \
            *(bf16x8*)(ldsAw + (SN_) + 12288) = cvt8(rA[6], rA[7]);            \
        }                                                                      \
        if (STGAL_) {                                                          \
            _Pragma("unroll") for (int j = 0; j < 4; ++j) {                    \
                rA[2*j]   = *(const float4*)(AfN + (KO_) + (long)j * 65536);   \
                rA[2*j+1] = *(const float4*)(AfN + (KO_) + (long)j * 65536 + 4);\
            }                                                                  \
        }                                                                      \
        __builtin_amdgcn_s_barrier();                                          \
        LGKM0();                                                               \
        MFMA16(a0, b0, 0);                                                     \
        __builtin_amdgcn_s_barrier();                                          \
        /* ph2: read a0h,b1 */                                                 \
        _Pragma("unroll") for (int mi = 0; mi < 4; ++mi)                       \
            a0h[mi] = *(const bf16x8*)(aK1 + (SO_) + mi * 1024);               \
        _Pragma("unroll") for (int ni = 0; ni < 4; ++ni)                       \
            b1[ni]  = *(const bf16x8*)(bK1 + (SO_) + ni * 1024);               \
        __builtin_amdgcn_s_barrier();                                          \
        LGKM0();                                                               \
        MFMA16(a0h, b1, 0);                                                    \
        __builtin_amdgcn_s_barrier();                                          \
        /* ph3: read a1; stage B(KT+2) half0 -> slot SO */                     \
        _Pragma("unroll") for (int mi = 0; mi < 4; ++mi)                       \
            a1[mi] = *(const bf16x8*)(aK0 + (SO_) + (mi + 4) * 1024);          \
        if (STGB_) {                                                           \
            _Pragma("unroll") for (int j = 0; j < 2; ++j)                      \
                GLDA(BgN + (KO_) + (long)j * 65536,                            \
                     ldsBf + (SO_) + j * 4096 + ldst);                         \
        }                                                                      \
        __builtin_amdgcn_s_barrier();                                          \
        LGKM0();                                                               \
        MFMA16(a1, b0, 4);                                                     \
        __builtin_amdgcn_s_barrier();                                          \
        /* ph4: read a1h; stage B(KT+2) half1; vmcnt; MFMA */                  \
        _Pragma("unroll") for (int mi = 0; mi < 4; ++mi)                       \
            a1h[mi] = *(const bf16x8*)(aK1 + (SO_) + (mi + 4) * 1024);         \
        if (STGB_) {                                                           \
            _Pragma("unroll") for (int j = 0; j < 2; ++j)                      \
                GLDA(BgN + (KO_) + 131072 + (long)j * 65536,                   \
                     ldsBf + (SO_) + 8192 + j * 4096 + ldst);                  \
        }                                                                      \
        if ((VM_) == 12)     { asm volatile("s_waitcnt vmcnt(12)" ::: "memory"); } \
        else if ((VM_) == 0) { asm volatile("s_waitcnt vmcnt(0)" ::: "memory"); }  \
        __builtin_amdgcn_sched_barrier(0);                                     \
        __builtin_amdgcn_s_barrier();                                          \
        LGKM0();                                                               \
        MFMA16(a1h, b1, 4);                                                    \
        __builtin_amdgcn_s_barrier();                                          \
    }

    #pragma unroll 1
    for (int ii = 0; ii < 7; ++ii) {       // KT 0..13
        KTBODY(0,     16384, 0,  1, 1, 1, 12);
        KTBODY(16384, 0,     64, 1, 1, 1, 12);
        AfN += 128; BgN += 128;
    }
    KTBODY(0,     16384, 0, 1, 0, 0, 0);   // KT14: write A(15), drain
    KTBODY(16384, 0,     0, 0, 0, 0, -1);  // KT15: final
    #undef KTBODY
    #undef MFMA16
    #undef LGKM0
    #undef GLDA

    // ------------------ epilogue ------------------
    // Transposed D: element (row = wm*128+mi*16+fr, col = wn*64+ni*16+g4*4+j).
    // One bf16x4 store per (mi,ni). Lane-local mean partial over b = fr+16*(mi&1).
    const int g4 = lane >> 4;
    const long colb = col0 + wn * 64 + g4 * 4;

    float4 bias4[4];
    #pragma unroll
    for (int ni = 0; ni < 4; ++ni)
        bias4[ni] = *(const float4*)(bias + colb + ni * 16);

    f32x4 msum[2][4];
    #pragma unroll
    for (int bh = 0; bh < 2; ++bh)
        #pragma unroll
        for (int ni = 0; ni < 4; ++ni)
            msum[bh][ni] = f32x4{0.f, 0.f, 0.f, 0.f};

    #pragma unroll
    for (int mi = 0; mi < 8; ++mi) {
        const long row = row0 + wm * 128 + mi * 16 + fr;
        #pragma unroll
        for (int ni = 0; ni < 4; ++ni) {
            f32x4 xv;
            xv[0] = acc[mi][ni][0] + bias4[ni].x;
            xv[1] = acc[mi][ni][1] + bias4[ni].y;
            xv[2] = acc[mi][ni][2] + bias4[ni].z;
            xv[3] = acc[mi][ni][3] + bias4[ni].w;
            bf16x4 xb;
            xb[0] = (__bf16)xv[0]; xb[1] = (__bf16)xv[1];
            xb[2] = (__bf16)xv[2]; xb[3] = (__bf16)xv[3];
            *(bf16x4*)(X + row * 1024 + colb + ni * 16) = xb;
            msum[mi & 1][ni] += xv;
        }
    }

    // cross-wave (wm) reduce of mean partials through LDS (free after K-loop)
    float* ldsf = (float*)ldsAf;          // 32 b x 256 n f32 = 32 KB
    __syncthreads();                      // all K-loop LDS traffic done
    if (wm == 1) {
        #pragma unroll
        for (int bh = 0; bh < 2; ++bh)
            #pragma unroll
            for (int ni = 0; ni < 4; ++ni)
                *(f32x4*)(ldsf + (bh * 16 + fr) * 256 + wn * 64 + ni * 16 + g4 * 4) = msum[bh][ni];
    }
    __syncthreads();
    if (wm == 0) {
        #pragma unroll
        for (int bh = 0; bh < 2; ++bh) {
            const int b = bh * 16 + fr;
            #pragma unroll
            for (int ni = 0; ni < 4; ++ni) {
                f32x4 other = *(const f32x4*)(ldsf + b * 256 + wn * 64 + ni * 16 + g4 * 4);
                f32x4 tot = msum[bh][ni] + other;
                *(f32x4*)(mpart + ((long)bm * 32 + b) * 1024 + colb + ni * 16) = tot;
            }
        }
    }
}

// ---------------------------------------------------------------------------
// K3: finalize mean from fused partials, gate2[b,h,q] = tanh(m.Wm[q]+bWm[q]).
// ---------------------------------------------------------------------------
__global__ __launch_bounds__(256)
void gate2_k(const float* __restrict__ mpart, const float* __restrict__ Wm,
             const float* __restrict__ bWm, float* __restrict__ g2)
{
    __shared__ float mrow[1024];
    const int b = blockIdx.x;
    const int j4 = threadIdx.x * 4;
    f32x4 s = f32x4{0.f, 0.f, 0.f, 0.f};
    for (int bm = 0; bm < 256; ++bm)
        s += *(const f32x4*)(mpart + ((long)bm * 32 + b) * 1024 + j4);
    mrow[j4 + 0] = s[0] * (1.0f / 2048.0f);
    mrow[j4 + 1] = s[1] * (1.0f / 2048.0f);
    mrow[j4 + 2] = s[2] * (1.0f / 2048.0f);
    mrow[j4 + 3] = s[3] * (1.0f / 2048.0f);
    __syncthreads();
    if (threadIdx.x < 128) {
        const int h = threadIdx.x >> 4;
        const int q = threadIdx.x & 15;
        float d = bWm[q];
        #pragma unroll 8
        for (int k = 0; k < 128; ++k) d += mrow[h * 128 + k] * Wm[q * 128 + k];
        g2[(b * 8 + h) * 16 + q] = tanhf(d);
    }
}

// ---------------------------------------------------------------------------
// K4: scores. X viewed as (524288 rows = bt*8+h, 128). One wave = 16 rows.
// ---------------------------------------------------------------------------
__global__ __launch_bounds__(256)
void scores_k(const __bf16* __restrict__ X, const float* __restrict__ W,
              const float* __restrict__ bW, const float* __restrict__ g2,
              const float* __restrict__ Wh, const float* __restrict__ bWh,
              float* __restrict__ sbuf)
{
    const int tid   = threadIdx.x;
    const int lane  = tid & 63;
    const int w     = tid >> 6;
    const int gw    = blockIdx.x * 4 + w;
    const int rbase = gw * 16;
    const int q     = lane & 15;
    const int g4    = lane >> 4;

    bf16x8 bfr[4];
    #pragma unroll
    for (int c = 0; c < 4; ++c) {
        const float* wp = W + q * 128 + c * 32 + g4 * 8;
        float4 w0 = *(const float4*)wp;
        float4 w1 = *(const float4*)(wp + 4);
        bfr[c] = cvt8(w0, w1);
    }
    const __bf16* xp = X + (long)(rbase + q) * 128 + g4 * 8;
    bf16x8 afr[4];
    #pragma unroll
    for (int c = 0; c < 4; ++c) afr[c] = *(const bf16x8*)(xp + c * 32);

    f32x4 acc = f32x4{0.f, 0.f, 0.f, 0.f};
    #pragma unroll
    for (int c = 0; c < 4; ++c)
        acc = __builtin_amdgcn_mfma_f32_16x16x32_bf16(afr[c], bfr[c], acc, 0, 0, 0);

    const float whq  = Wh[q];
    const float bWv  = bW[q];
    const float bWhv = *bWh;
    #pragma unroll
    for (int r = 0; r < 4; ++r) {
        const int row = rbase + g4 * 4 + r;
        const int h   = row & 7;
        const int bt  = row >> 3;
        const int b   = bt & 31;
        const int t   = bt >> 5;
        float val = tanhf(acc[r] + bWv) * g2[(b * 8 + h) * 16 + q] * whq;
        val += __shfl_xor(val, 1);
        val += __shfl_xor(val, 2);
        val += __shfl_xor(val, 4);
        val += __shfl_xor(val, 8);
        if (q == 0) sbuf[(b * 8 + h) * 2048 + t] = val + bWhv;
    }
}

// ---------------------------------------------------------------------------
// K5: softmax over t, in place. 256 blocks (b*8+h).
// ---------------------------------------------------------------------------
__global__ __launch_bounds__(256)
void softmax_k(float* __restrict__ s)
{
    __shared__ float red[256];
    const int bh = blockIdx.x;
    const int tid = threadIdx.x;
    float* row = s + bh * 2048;
    float4 v0 = *(const float4*)(row + tid * 8);
    float4 v1 = *(const float4*)(row + tid * 8 + 4);
    float v[8] = {v0.x, v0.y, v0.z, v0.w, v1.x, v1.y, v1.z, v1.w};
    float mx = v[0];
    #pragma unroll
    for (int i = 1; i < 8; ++i) mx = fmaxf(mx, v[i]);
    red[tid] = mx;
    __syncthreads();
    for (int st = 128; st > 0; st >>= 1) {
        if (tid < st) red[tid] = fmaxf(red[tid], red[tid + st]);
        __syncthreads();
    }
    mx = red[0];
    __syncthreads();
    float sum = 0.f;
    #pragma unroll
    for (int i = 0; i < 8; ++i) { v[i] = expf(v[i] - mx); sum += v[i]; }
    red[tid] = sum;
    __syncthreads();
    for (int st = 128; st > 0; st >>= 1) {
        if (tid < st) red[tid] += red[tid + st];
        __syncthreads();
    }
    const float inv = 1.0f / red[0];
    *(float4*)(row + tid * 8)     = make_float4(v[0] * inv, v[1] * inv, v[2] * inv, v[3] * inv);
    *(float4*)(row + tid * 8 + 4) = make_float4(v[4] * inv, v[5] * inv, v[6] * inv, v[7] * inv);
}

// ---------------------------------------------------------------------------
// K6: weighted sum over t, t split 8 ways. 2048 blocks.
// ---------------------------------------------------------------------------
__global__ __launch_bounds__(256)
void wsum_k(const float* __restrict__ a, const __bf16* __restrict__ X,
            float* __restrict__ wpart)
{
    __shared__ float pk[8 * 128];
    const int bx = blockIdx.x;
    const int tc = bx & 7;
    const int bh = bx >> 3;
    const int b  = bh >> 3;
    const int h  = bh & 7;
    const int tid = threadIdx.x;
    const int kq = tid & 31;
    const int tr = tid >> 5;
    const float* ar = a + bh * 2048 + tc * 256;
    float a0 = 0.f, a1 = 0.f, a2 = 0.f, a3 = 0.f;
    #pragma unroll 4
    for (int i = tr; i < 256; i += 8) {
        const int t = tc * 256 + i;
        const float av = ar[i];
        bf16x4 xv = *(const bf16x4*)(X + (long)(t * 32 + b) * 1024 + h * 128 + kq * 4);
        a0 += av * (float)xv[0];
        a1 += av * (float)xv[1];
        a2 += av * (float)xv[2];
        a3 += av * (float)xv[3];
    }
    pk[tr * 128 + kq * 4 + 0] = a0;
    pk[tr * 128 + kq * 4 + 1] = a1;
    pk[tr * 128 + kq * 4 + 2] = a2;
    pk[tr * 128 + kq * 4 + 3] = a3;
    __syncthreads();
    if (tid < 128) {
        float s2 = 0.f;
        #pragma unroll
        for (int r = 0; r < 8; ++r) s2 += pk[r * 128 + tid];
        wpart[(long)bx * 128 + tid] = s2;
    }
}

// K7: reduce the 8 t-chunks.
__global__ __launch_bounds__(256)
void wsum_fin(const float* __restrict__ wpart, float* __restrict__ out)
{
    const int idx = blockIdx.x * 256 + threadIdx.x;
    const int k  = idx & 127;
    const int bh = idx >> 7;
    const int b  = bh >> 3;
    const int h  = bh & 7;
    float s = 0.f;
    #pragma unroll
    for (int tc = 0; tc < 8; ++tc) s += wpart[(bh * 8 + tc) * 128 + k];
    out[b * 1024 + h * 128 + k] = s;
}

extern "C" void kernel_launch(void* const* d_in, const int* in_sizes, int n_in,
                              void* d_out, int out_size, void* d_ws, size_t ws_size,
                              hipStream_t stream)
{
    const float* hyp = (const float*)d_in[0];
    const float* Wmh = (const float*)d_in[1];
    const float* bmh = (const float*)d_in[2];
    const float* W   = (const float*)d_in[3];
    const float* bW  = (const float*)d_in[4];
    const float* Wm  = (const float*)d_in[5];
    const float* bWm = (const float*)d_in[6];
    const float* Wh  = (const float*)d_in[7];
    const float* bWh = (const float*)d_in[8];
    float* out = (float*)d_out;

    char* ws = (char*)d_ws;
    const size_t SZ_X   = 134217728;   // X bf16 (65536 x 1024)
    const size_t SZ_BB  = 2097152;     // Bb bf16 Wmh
    const size_t SZ_MP  = 33554432;    // mpart f32 (256 x 32 x 1024)
    const size_t SZ_G2  = 16384;
    const size_t SZ_SB  = 2097152;

    size_t off = 0;
    __bf16* X     = (__bf16*)(ws + off); off += SZ_X;
    __bf16* Bb    = (__bf16*)(ws + off); off += SZ_BB;
    float*  mpart = (float*) (ws + off); off += SZ_MP;
    float*  g2    = (float*) (ws + off); off += SZ_G2;
    float*  sbuf  = (float*) (ws + off); off += SZ_SB;
    float*  wpart = (float*) (ws + off);

    cvt_f32_bf16<<<512, 256, 0, stream>>>(Wmh, Bb);
    gemm_x_8ph<<<1024, 512, 0, stream>>>(hyp, Bb, bmh, X, mpart);
    gate2_k<<<32, 256, 0, stream>>>(mpart, Wm, bWm, g2);
    scores_k<<<8192, 256, 0, stream>>>(X, W, bW, g2, Wh, bWh, sbuf);
    softmax_k<<<256, 256, 0, stream>>>(sbuf);
    wsum_k<<<2048, 256, 0, stream>>>(sbuf, X, wpart);
    wsum_fin<<<128, 256, 0, stream>>>(wpart, out);
}